// Round 13
// baseline (323.283 us; speedup 1.0000x reference)
//
#include <hip/hip_runtime.h>
#include <hip/hip_bf16.h>

// WanSelfAttention: x[1,3584,1536] -> QKV proj -> RMSNorm(full dim) -> 3D RoPE
// -> 12-head attention (HD=128) -> out proj. All matmuls bf16 MFMA, f32 accum.

#define DIM   1536
#define HEADS 12
#define HD    128
#define LSEQ  3584

typedef __bf16 bf16_t;
typedef __attribute__((ext_vector_type(8))) __bf16 bf16x8;
typedef __attribute__((ext_vector_type(4))) float f32x4;
typedef __attribute__((ext_vector_type(16))) float f32x16;
typedef unsigned int u32;
typedef __attribute__((ext_vector_type(2))) unsigned int u32x2;
typedef __attribute__((ext_vector_type(4))) unsigned int u32x4;

static __device__ __forceinline__ ushort f2bf(float f) {
  bf16_t h = (bf16_t)f;
  return __builtin_bit_cast(ushort, h);
}
static __device__ __forceinline__ float bf2f(ushort u) {
  return (float)__builtin_bit_cast(bf16_t, u);
}
static __device__ __forceinline__ u32 pkbf(float a, float b) {
  return (u32)f2bf(a) | ((u32)f2bf(b) << 16);
}

// exchange: lanes>=32 half of x swaps with lanes<32 half of y.
static __device__ __forceinline__ void plswap(u32& x, u32& y, int hi) {
#if __has_builtin(__builtin_amdgcn_permlane32_swap)
  (void)hi;
  u32x2 r = __builtin_amdgcn_permlane32_swap(x, y, false, false);
  x = r[0]; y = r[1];
#else
  u32 sx = __shfl_xor(x, 32, 64);
  u32 sy = __shfl_xor(y, 32, 64);
  u32 nx = hi ? sy : x;
  u32 ny = hi ? y : sx;
  x = nx; y = ny;
#endif
}

// ---------------- f32 -> bf16 converts ----------------
__global__ __launch_bounds__(256) void cvt_f32_bf16(const float* __restrict__ in,
                                                    ushort* __restrict__ out, int n) {
  int i = (blockIdx.x * 256 + threadIdx.x) * 4;
  if (i + 3 < n) {
    float4 v = *reinterpret_cast<const float4*>(in + i);
    ushort4 o;
    o.x = f2bf(v.x); o.y = f2bf(v.y); o.z = f2bf(v.z); o.w = f2bf(v.w);
    *reinterpret_cast<ushort4*>(out + i) = o;
  }
}

// 4 weight matrices (same size WD) -> contiguous bf16 dst, one launch
__global__ __launch_bounds__(256) void cvt_w4(const float* __restrict__ s0,
                                              const float* __restrict__ s1,
                                              const float* __restrict__ s2,
                                              const float* __restrict__ s3,
                                              ushort* __restrict__ dst) {
  const int WD4 = (DIM * DIM) / 4;          // float4s per matrix
  const int per = WD4 / 256;                // blocks per matrix
  int mat = blockIdx.x / per;
  int rb  = blockIdx.x % per;
  const float* s = mat == 0 ? s0 : (mat == 1 ? s1 : (mat == 2 ? s2 : s3));
  int i = (rb * 256 + threadIdx.x) * 4;
  float4 v = *reinterpret_cast<const float4*>(s + i);
  ushort4 o;
  o.x = f2bf(v.x); o.y = f2bf(v.y); o.z = f2bf(v.z); o.w = f2bf(v.w);
  *reinterpret_cast<ushort4*>(dst + (size_t)mat * DIM * DIM + i) = o;
}

// ---------------- GEMM: C = A[M][K] @ B[N][K]^T + bias (persistent grid) ----
// BK=64, LDS [128][64] with T2 XOR-swizzle (byte ^= (row&7)<<4) applied via
// pre-swizzled global_load_lds SOURCE + XOR on ds_read (m173 pattern).
// SEGS=3: B is 3 stacked weights; output 3 stacked buffers; bias per segment.
template <int SEGS, bool OUT_F32>
__global__ __launch_bounds__(256) void gemm_bt(const ushort* __restrict__ A,
                                               const ushort* __restrict__ B,
                                               const float* __restrict__ bias0,
                                               const float* __restrict__ bias1,
                                               const float* __restrict__ bias2,
                                               void* __restrict__ Cout) {
  const int K = DIM;
  const int MT = LSEQ / 128;            // 28
  const int ntiles = MT * (SEGS * DIM / 128);
  __shared__ __attribute__((aligned(16))) ushort As[128 * 64];
  __shared__ __attribute__((aligned(16))) ushort Bs[128 * 64];
  const int tid  = threadIdx.x;
  const int lane = tid & 63;
  const int wid  = tid >> 6;
  const int wm = (wid >> 1) * 64;
  const int wn = (wid & 1) * 64;
  const int lr = lane & 15;
  const int lg = lane >> 4;
  // staging geometry: chunk = 8 rows x 64 cols (1 KB); lane covers 16 B
  const int srow = lane >> 3;           // row within chunk (0..7)
  const int sbyte = (lane & 7) * 16;    // byte col within row
  const int ssrc = (sbyte ^ (srow << 4)) >> 1;  // pre-swizzled ushort col

  for (int tile = blockIdx.x; tile < ntiles; tile += gridDim.x) {
    const int m0 = (tile % MT) * 128;
    const int n0 = (tile / MT) * 128;   // consecutive blocks share B panel

    f32x4 acc[4][4] = {};

    for (int kt = 0; kt < K; kt += 64) {
      __syncthreads();
#pragma unroll
      for (int i = 0; i < 4; ++i) {
        int chunk = wid * 4 + i;               // 0..15 -> rows [chunk*8, +8)
        int row = chunk * 8 + srow;
        const ushort* ga = A + (size_t)(m0 + row) * K + kt + ssrc;
        const ushort* gb = B + (size_t)(n0 + row) * K + kt + ssrc;
        __builtin_amdgcn_global_load_lds(
            (__attribute__((address_space(1))) void*)(void*)ga,
            (__attribute__((address_space(3))) void*)(&As[chunk * 512]), 16, 0, 0);
        __builtin_amdgcn_global_load_lds(
            (__attribute__((address_space(1))) void*)(void*)gb,
            (__attribute__((address_space(3))) void*)(&Bs[chunk * 512]), 16, 0, 0);
      }
      __syncthreads();

#pragma unroll
      for (int kk = 0; kk < 2; ++kk) {
        bf16x8 af[4], bfr[4];
        const int cb = lg * 16 + kk * 64;      // byte col of this lane's frag
#pragma unroll
        for (int m = 0; m < 4; ++m) {
          int row = wm + m * 16 + lr;
          af[m] = *reinterpret_cast<const bf16x8*>(
              (const char*)As + row * 128 + (cb ^ ((row & 7) << 4)));
        }
#pragma unroll
        for (int n = 0; n < 4; ++n) {
          int row = wn + n * 16 + lr;
          bfr[n] = *reinterpret_cast<const bf16x8*>(
              (const char*)Bs + row * 128 + (cb ^ ((row & 7) << 4)));
        }
#pragma unroll
        for (int m = 0; m < 4; ++m)
#pragma unroll
          for (int n = 0; n < 4; ++n)
            acc[m][n] = __builtin_amdgcn_mfma_f32_16x16x32_bf16(af[m], bfr[n], acc[m][n], 0, 0, 0);
      }
    }

    int seg = 0;
    const float* bp = bias0;
    if (SEGS == 3) {
      seg = n0 >= 2 * DIM ? 2 : (n0 >= DIM ? 1 : 0);
      bp = seg == 0 ? bias0 : (seg == 1 ? bias1 : bias2);
    }
    const int nbase = n0 - seg * DIM;

#pragma unroll
    for (int m = 0; m < 4; ++m) {
#pragma unroll
      for (int n = 0; n < 4; ++n) {
        int col = nbase + wn + n * 16 + lr;
        float bvv = bp[col];
#pragma unroll
        for (int r = 0; r < 4; ++r) {
          int row = m0 + wm + m * 16 + lg * 4 + r;
          float v = acc[m][n][r] + bvv;
          if (OUT_F32)
            ((float*)Cout)[(size_t)row * DIM + col] = v;
          else
            ((ushort*)Cout)[(size_t)seg * ((size_t)LSEQ * DIM) + (size_t)row * DIM + col] = f2bf(v);
        }
      }
    }
    __syncthreads();  // all reads of As/Bs done before next tile stages
  }
}

// ---------------- RMSNorm(full 1536) + 3D RoPE, in place on bf16 ----------------
__global__ __launch_bounds__(256) void normrope(ushort* __restrict__ Qb,
                                                ushort* __restrict__ Kb,
                                                const float* __restrict__ gq,
                                                const float* __restrict__ gk,
                                                const float* __restrict__ cosT,
                                                const float* __restrict__ sinT) {
  __shared__ float red[4];
  const int l = blockIdx.x;
  const int tid = threadIdx.x;
  ushort* row = (blockIdx.y == 0 ? Qb : Kb) + (size_t)l * DIM;
  const float* g = blockIdx.y == 0 ? gq : gk;

  const u32* rp = reinterpret_cast<const u32*>(row);
  u32 pk[3];
  float v[6];
#pragma unroll
  for (int i = 0; i < 3; ++i) {
    pk[i] = rp[tid * 3 + i];
    v[2 * i]     = bf2f((ushort)(pk[i] & 0xffff));
    v[2 * i + 1] = bf2f((ushort)(pk[i] >> 16));
  }
  float ss = 0.f;
#pragma unroll
  for (int i = 0; i < 6; ++i) ss += v[i] * v[i];
#pragma unroll
  for (int off = 1; off < 64; off <<= 1) ss += __shfl_xor(ss, off, 64);
  if ((tid & 63) == 0) red[tid >> 6] = ss;
  __syncthreads();
  float tot = red[0] + red[1] + red[2] + red[3];
  float rms = rsqrtf(tot * (1.0f / DIM) + 1e-6f);

  const int fi = l / 448;
  const int rem = l % 448;
  const int hi = rem / 28;
  const int wi = rem % 28;

  u32* wp = reinterpret_cast<u32*>(row);
#pragma unroll
  for (int i = 0; i < 3; ++i) {
    int p = tid * 3 + i;
    int head = p >> 6;
    int j = p & 63;
    int trow = (j < 22) ? fi : ((j < 43) ? hi : wi);
    float cv = cosT[trow * 64 + j];
    float sv = sinT[trow * 64 + j];
    int idx = head * 128 + 2 * j;
    float xr = v[2 * i] * rms * g[idx];
    float xi = v[2 * i + 1] * rms * g[idx + 1];
    float orr = xr * cv - xi * sv;
    float oii = xr * sv + xi * cv;
    wp[p] = (u32)f2bf(orr) | ((u32)f2bf(oii) << 16);
  }
}

// ---------------- flash attention: 4 waves x 32 q-rows, KVB=64, 32x32 MFMA.
// Ks double-buffered (DMA lands during compute); Vt SINGLE-buffered (staged
// through regs; writeV only after the barrier separating it from prior reads)
// -> LDS ~50KB -> 3 blocks/CU. P in-register via permlane (T12). XCD remap (T1).
#define QBLK 128
#define KVB  64

__global__ __launch_bounds__(256, 2) void attn(const ushort* __restrict__ Q,
                                               const ushort* __restrict__ Kp,
                                               const ushort* __restrict__ Vp,
                                               ushort* __restrict__ O,
                                               float* __restrict__ Opart,
                                               float* __restrict__ mlbuf,
                                               int nsplit) {
  __shared__ __attribute__((aligned(16))) ushort Ks[2][KVB * 128];  // 2x16KB
  __shared__ __attribute__((aligned(16))) ushort Vt[128][72];       // 18KB single
  const int tid  = threadIdx.x;
  const int lane = tid & 63;
  const int wv   = tid >> 6;
  const int lq   = lane & 31;
  const int hi   = lane >> 5;
  const float scale = 0.08838834764831845f; // 1/sqrt(128)

  // T1: remap so each XCD gets a contiguous tile range (KV slice L2 reuse).
  const int per_xcd = gridDim.x >> 3;
  const int tile = (blockIdx.x & 7) * per_xcd + (blockIdx.x >> 3);
  const int qb    = tile % (LSEQ / QBLK);          // q-block fastest
  const int rest  = tile / (LSEQ / QBLK);
  const int h     = rest % HEADS;
  const int split = rest / HEADS;
  const int q0    = qb * QBLK;

  const int NT   = LSEQ / KVB;                 // 56 tiles
  const int t_lo = split * NT / nsplit;
  const int t_hi = (split + 1) * NT / nsplit;

  // Q fragments (B-operand): lane holds Q[q=lq][d = dstep*16 + hi*8 + j]
  bf16x8 qf[8];
  {
    const ushort* qbase = Q + (size_t)(q0 + wv * 32 + lq) * DIM + h * HD;
#pragma unroll
    for (int d = 0; d < 8; ++d)
      qf[d] = *reinterpret_cast<const bf16x8*>(qbase + d * 16 + hi * 8);
  }

  f32x16 accO[4] = {}; // [nd]: col d = nd*32+lq, row q = crow(r,hi)
  float m = -1e30f, lsum = 0.f;

  const int mbk = tid >> 4;  // 0..15 -> kv rows [4*mbk, +4)
  const int mbd = tid & 15;  // 0..15 -> d cols  [8*mbd, +8)

  uint4 vr0, vr1, vr2, vr3;  // next tile's V rows (4x8 micro-block)
  auto issueK = [&](int t, int nb) {
    const int kv0 = t * KVB;
#pragma unroll
    for (int i = 0; i < 4; ++i) {
      int o16 = (wv * 4 + i) * 64 + lane;        // 16B-unit index in tile
      int r = o16 >> 4;
      int b = (o16 & 15) * 16;                   // byte col within row
      int srcu = (b ^ ((r & 7) << 4)) >> 1;      // pre-swizzled ushort col
      const ushort* gp = Kp + (size_t)(kv0 + r) * DIM + h * HD + srcu;
      __builtin_amdgcn_global_load_lds(
          (__attribute__((address_space(1))) void*)(void*)gp,
          (__attribute__((address_space(3))) void*)(&Ks[nb][(wv * 4 + i) * 512]), 16, 0, 0);
    }
  };
  auto loadV = [&](int t) {
    const ushort* vbase = Vp + (size_t)(t * KVB + mbk * 4) * DIM + h * HD + mbd * 8;
    vr0 = *reinterpret_cast<const uint4*>(vbase);
    vr1 = *reinterpret_cast<const uint4*>(vbase + DIM);
    vr2 = *reinterpret_cast<const uint4*>(vbase + 2 * DIM);
    vr3 = *reinterpret_cast<const uint4*>(vbase + 3 * DIM);
  };
  auto writeV = [&]() {
    const ushort* s0 = reinterpret_cast<const ushort*>(&vr0);
    const ushort* s1 = reinterpret_cast<const ushort*>(&vr1);
    const ushort* s2 = reinterpret_cast<const ushort*>(&vr2);
    const ushort* s3 = reinterpret_cast<const ushort*>(&vr3);
#pragma unroll
    for (int jj = 0; jj < 8; ++jj) {
      int j = (jj + mbd) & 7;  // rotate write order to spread banks
      uint2 w;
      w.x = (u32)s0[j] | ((u32)s1[j] << 16);
      w.y = (u32)s2[j] | ((u32)s3[j] << 16);
      *reinterpret_cast<uint2*>(&Vt[mbd * 8 + j][mbk * 4]) = w;
    }
  };

  issueK(t_lo, 0);
  loadV(t_lo);

  int buf = 0;
  for (int t = t_lo; t < t_hi; ++t) {
    writeV();          // V_t regs -> Vt (prior reads separated by loop-end barrier)
    __syncthreads();   // K DMA (vmcnt) + Vt writes of this tile visible

    if (t + 1 < t_hi) {      // prefetch next tile; lands during compute
      issueK(t + 1, buf ^ 1);
      loadV(t + 1);
    }

    // ---- two sequential 32-k subtiles (one sv live) ----
#pragma unroll
    for (int hf = 0; hf < 2; ++hf) {
      f32x16 sv = {};
      __builtin_amdgcn_s_setprio(1);
#pragma unroll
      for (int d = 0; d < 8; ++d) {
        int db = d * 32 + hi * 16;   // byte col of this lane's 16B A-chunk
        const bf16x8 a = *reinterpret_cast<const bf16x8*>(
            (const char*)&Ks[buf][0] + (hf * 32 + lq) * 256 + (db ^ ((lq & 7) << 4)));
        sv = __builtin_amdgcn_mfma_f32_32x32x16_bf16(a, qf[d], sv, 0, 0, 0);
      }
      __builtin_amdgcn_s_setprio(0);

      // softmax over this 32-k subtile (lane owns q-row; partner has other 16 k)
      float pmax = sv[0];
#pragma unroll
      for (int r = 1; r < 16; ++r) pmax = fmaxf(pmax, sv[r]);
      pmax = fmaxf(pmax, __shfl_xor(pmax, 32, 64));
      pmax *= scale;

      if (__any(pmax > m + 8.f)) {   // defer-max (T13)
        float mn = fmaxf(m, pmax);
        float al = __expf(m - mn);
        m = mn;
        lsum *= al;
#pragma unroll
        for (int r = 0; r < 16; ++r) {
          int qr = (r & 3) + 8 * (r >> 2) + 4 * hi;
          float alr = __shfl(al, qr, 64);
          accO[0][r] *= alr; accO[1][r] *= alr;
          accO[2][r] *= alr; accO[3][r] *= alr;
        }
      }

      float p[16];
      float psum = 0.f;
#pragma unroll
      for (int r = 0; r < 16; ++r) {
        p[r] = __expf(fmaf(sv[r], scale, -m));
        psum += p[r];
      }
      psum += __shfl_xor(psum, 32, 64);
      lsum += psum;

      // ---- in-register P -> A-fragment redistribution (T12) ----
      u32 a0 = pkbf(p[0], p[1]),   a1 = pkbf(p[2], p[3]);
      u32 a4 = pkbf(p[4], p[5]),   a5 = pkbf(p[6], p[7]);
      u32 c0 = pkbf(p[8], p[9]),   c1 = pkbf(p[10], p[11]);
      u32 c4 = pkbf(p[12], p[13]), c5 = pkbf(p[14], p[15]);
      plswap(a0, a4, hi);
      plswap(a1, a5, hi);
      plswap(c0, c4, hi);
      plswap(c1, c5, hi);
      u32x4 w0 = {a0, a1, a4, a5};
      u32x4 w1 = {c0, c1, c4, c5};
      bf16x8 pa0 = __builtin_bit_cast(bf16x8, w0);  // k [hf*32, +16)
      bf16x8 pa1 = __builtin_bit_cast(bf16x8, w1);  // k [hf*32+16, +16)

      // ---- PV over this 32-k subtile ----
      __builtin_amdgcn_s_setprio(1);
#pragma unroll
      for (int nd = 0; nd < 4; ++nd) {
        bf16x8 vb0 = *reinterpret_cast<const bf16x8*>(
            &Vt[nd * 32 + lq][hf * 32 + hi * 8]);
        accO[nd] = __builtin_amdgcn_mfma_f32_32x32x16_bf16(pa0, vb0, accO[nd], 0, 0, 0);
      }
#pragma unroll
      for (int nd = 0; nd < 4; ++nd) {
        bf16x8 vb1 = *reinterpret_cast<const bf16x8*>(
            &Vt[nd * 32 + lq][hf * 32 + 16 + hi * 8]);
        accO[nd] = __builtin_amdgcn_mfma_f32_32x32x16_bf16(pa1, vb1, accO[nd], 0, 0, 0);
      }
      __builtin_amdgcn_s_setprio(0);
    }

    __syncthreads();  // Ks[buf]/Vt reads done before re-stage
    buf ^= 1;
  }

  // ---- epilogue ----
  if (nsplit == 1) {
    float inv_own = 1.0f / lsum;
#pragma unroll
    for (int r = 0; r < 16; ++r) {
      int qr = (r & 3) + 8 * (r >> 2) + 4 * hi;
      float inv = __shfl(inv_own, qr, 64);
      ushort* orow = O + (size_t)(q0 + wv * 32 + qr) * DIM + h * HD;
#pragma unroll
      for (int nd = 0; nd < 4; ++nd)
        orow[nd * 32 + lq] = f2bf(accO[nd][r] * inv);
    }
  } else {
    float* Op = Opart + ((size_t)split * HEADS + h) * ((size_t)LSEQ * HD);
#pragma unroll
    for (int r = 0; r < 16; ++r) {
      int qr = (r & 3) + 8 * (r >> 2) + 4 * hi;
      float* orow = Op + (size_t)(q0 + wv * 32 + qr) * HD;
#pragma unroll
      for (int nd = 0; nd < 4; ++nd)
        orow[nd * 32 + lq] = accO[nd][r];
    }
    if (hi == 0) {
      size_t row = (size_t)split * (HEADS * LSEQ) + (size_t)h * LSEQ + (q0 + wv * 32 + lq);
      mlbuf[2 * row]     = m;
      mlbuf[2 * row + 1] = lsum;
    }
  }
}

// ---------------- merge of KV-split partials ----------------
__global__ __launch_bounds__(256) void attn_merge(const float* __restrict__ Opart,
                                                  const float* __restrict__ mlbuf,
                                                  ushort* __restrict__ Ob, int nsplit) {
  const int RN = HEADS * LSEQ;          // rows per split
  int gi = blockIdx.x * 256 + threadIdx.x;   // one float4 of one (h,q) row
  int row = gi >> 5;                    // h*LSEQ + q
  int d4 = (gi & 31) * 4;
  if (row >= RN) return;
  int h = row / LSEQ, q = row % LSEQ;

  float M = -1e30f;
  for (int s = 0; s < nsplit; ++s) M = fmaxf(M, mlbuf[2 * ((size_t)s * RN + row)]);
  float den = 0.f;
  float4 acc = {0.f, 0.f, 0.f, 0.f};
  for (int s = 0; s < nsplit; ++s) {
    float ms = mlbuf[2 * ((size_t)s * RN + row)];
    float ls = mlbuf[2 * ((size_t)s * RN + row) + 1];
    float w = __expf(ms - M);
    den += ls * w;
    const float4 o = *reinterpret_cast<const float4*>(
        &Opart[((size_t)s * RN + row) * HD + d4]);
    acc.x += w * o.x; acc.y += w * o.y; acc.z += w * o.z; acc.w += w * o.w;
  }
  float inv = 1.0f / den;
  ushort4 r;
  r.x = f2bf(acc.x * inv); r.y = f2bf(acc.y * inv);
  r.z = f2bf(acc.z * inv); r.w = f2bf(acc.w * inv);
  *reinterpret_cast<ushort4*>(&Ob[(size_t)q * DIM + h * HD + d4]) = r;
}

// ---------------- launch ----------------
extern "C" void kernel_launch(void* const* d_in, const int* in_sizes, int n_in,
                              void* d_out, int out_size, void* d_ws, size_t ws_size,
                              hipStream_t stream) {
  (void)in_sizes; (void)n_in; (void)out_size;
  const float* x    = (const float*)d_in[0];
  const float* cosT = (const float*)d_in[1];
  const float* sinT = (const float*)d_in[2];
  const float* Wq   = (const float*)d_in[3];
  const float* bq   = (const float*)d_in[4];
  const float* Wk   = (const float*)d_in[5];
  const float* bk   = (const float*)d_in[6];
  const float* Wv   = (const float*)d_in[7];
  const float* bv_in = (const float*)d_in[8];
  const float* Wo   = (const float*)d_in[9];
  const float* bo   = (const float*)d_in[10];
  const float* gq   = (const float*)d_in[11];
  const float* gk   = (const float*)d_in[12];

  const size_t LD = (size_t)LSEQ * DIM;
  const size_t WD = (size_t)DIM * DIM;
  const size_t base_bytes = (5 * LD + 4 * WD) * sizeof(ushort);
  if (ws_size < base_bytes) return;

  ushort* xb  = (ushort*)d_ws;
  ushort* Wqb = xb + LD;        // Wqb, Wkb, Wvb, Wob contiguous
  ushort* Wob = Wqb + 3 * WD;
  ushort* Qb  = Wob + WD;       // Qb, Kb, Vb contiguous (fused C)
  ushort* Kb  = Qb + LD;
  ushort* Vb  = Kb + LD;
  ushort* Ob  = Vb + LD;

  // KV-split sizing from available workspace (deterministic in ws_size)
  const size_t RN = (size_t)HEADS * LSEQ;              // 43008 rows
  const size_t split_bytes = RN * HD * 4 + RN * 8;     // O partial + (m,l)
  int nsplit = 1;
  if (ws_size >= base_bytes + 3 * split_bytes) nsplit = 3;
  else if (ws_size >= base_bytes + 2 * split_bytes) nsplit = 2;
  float* Opart = (float*)((char*)d_ws + base_bytes);
  float* mlbuf = Opart + (size_t)nsplit * RN * HD;

  cvt_f32_bf16<<<(int)(LD / 4 / 256), 256, 0, stream>>>(x, xb, (int)LD);
  cvt_w4<<<(int)(4 * WD / 4 / 256), 256, 0, stream>>>(Wq, Wk, Wv, Wo, Wqb);

  // fused QKV projection: 1008 tiles on a 768-block persistent grid
  {
    int nt = (LSEQ / 128) * (3 * DIM / 128);
    gemm_bt<3, false><<<nt < 768 ? nt : 768, 256, 0, stream>>>(
        xb, Wqb, bq, bk, bv_in, Qb);
  }

  normrope<<<dim3(LSEQ, 2), 256, 0, stream>>>(Qb, Kb, gq, gk, cosT, sinT);

  // 1D grid, XCD-remapped inside the kernel (336*nsplit divisible by 8)
  attn<<<(LSEQ / QBLK) * HEADS * nsplit, 256, 0, stream>>>(
      Qb, Kb, Vb, Ob, Opart, mlbuf, nsplit);
  if (nsplit > 1)
    attn_merge<<<(int)(RN * 32 / 256), 256, 0, stream>>>(Opart, mlbuf, Ob, nsplit);

  {
    int nt = (LSEQ / 128) * (DIM / 128);   // 336 tiles
    gemm_bt<1, true><<<nt < 768 ? nt : 768, 256, 0, stream>>>(
        Ob, Wob, bo, bo, bo, d_out);
  }
}

// Round 14
// 280.759 us; speedup vs baseline: 1.1515x; 1.1515x over previous
//
#include <hip/hip_runtime.h>
#include <hip/hip_bf16.h>

// WanSelfAttention: x[1,3584,1536] -> QKV proj -> RMSNorm(full dim) -> 3D RoPE
// -> 12-head attention (HD=128) -> out proj. All matmuls bf16 MFMA, f32 accum.

#define DIM   1536
#define HEADS 12
#define HD    128
#define LSEQ  3584

typedef __bf16 bf16_t;
typedef __attribute__((ext_vector_type(8))) __bf16 bf16x8;
typedef __attribute__((ext_vector_type(4))) float f32x4;
typedef __attribute__((ext_vector_type(16))) float f32x16;
typedef unsigned int u32;
typedef __attribute__((ext_vector_type(2))) unsigned int u32x2;
typedef __attribute__((ext_vector_type(4))) unsigned int u32x4;

static __device__ __forceinline__ ushort f2bf(float f) {
  bf16_t h = (bf16_t)f;
  return __builtin_bit_cast(ushort, h);
}
static __device__ __forceinline__ float bf2f(ushort u) {
  return (float)__builtin_bit_cast(bf16_t, u);
}
static __device__ __forceinline__ u32 pkbf(float a, float b) {
  return (u32)f2bf(a) | ((u32)f2bf(b) << 16);
}

// exchange: lanes>=32 half of x swaps with lanes<32 half of y.
static __device__ __forceinline__ void plswap(u32& x, u32& y, int hi) {
#if __has_builtin(__builtin_amdgcn_permlane32_swap)
  (void)hi;
  u32x2 r = __builtin_amdgcn_permlane32_swap(x, y, false, false);
  x = r[0]; y = r[1];
#else
  u32 sx = __shfl_xor(x, 32, 64);
  u32 sy = __shfl_xor(y, 32, 64);
  u32 nx = hi ? sy : x;
  u32 ny = hi ? y : sx;
  x = nx; y = ny;
#endif
}

// ---------------- f32 -> bf16 converts ----------------
__global__ __launch_bounds__(256) void cvt_f32_bf16(const float* __restrict__ in,
                                                    ushort* __restrict__ out, int n) {
  int i = (blockIdx.x * 256 + threadIdx.x) * 4;
  if (i + 3 < n) {
    float4 v = *reinterpret_cast<const float4*>(in + i);
    ushort4 o;
    o.x = f2bf(v.x); o.y = f2bf(v.y); o.z = f2bf(v.z); o.w = f2bf(v.w);
    *reinterpret_cast<ushort4*>(out + i) = o;
  }
}

// 4 weight matrices (same size WD) -> contiguous bf16 dst, one launch
__global__ __launch_bounds__(256) void cvt_w4(const float* __restrict__ s0,
                                              const float* __restrict__ s1,
                                              const float* __restrict__ s2,
                                              const float* __restrict__ s3,
                                              ushort* __restrict__ dst) {
  const int WD4 = (DIM * DIM) / 4;          // float4s per matrix
  const int per = WD4 / 256;                // blocks per matrix
  int mat = blockIdx.x / per;
  int rb  = blockIdx.x % per;
  const float* s = mat == 0 ? s0 : (mat == 1 ? s1 : (mat == 2 ? s2 : s3));
  int i = (rb * 256 + threadIdx.x) * 4;
  float4 v = *reinterpret_cast<const float4*>(s + i);
  ushort4 o;
  o.x = f2bf(v.x); o.y = f2bf(v.y); o.z = f2bf(v.z); o.w = f2bf(v.w);
  *reinterpret_cast<ushort4*>(dst + (size_t)mat * DIM * DIM + i) = o;
}

// ---------------- GEMM: C = A[M][K] @ B[N][K]^T + bias (persistent grid) ----
// BK=64, LDS [128][64] with T2 XOR-swizzle (byte ^= (row&7)<<4) applied via
// pre-swizzled global_load_lds SOURCE + XOR on ds_read (m173 pattern).
// SEGS=3: B is 3 stacked weights; output 3 stacked buffers; bias per segment.
template <int SEGS, bool OUT_F32>
__global__ __launch_bounds__(256) void gemm_bt(const ushort* __restrict__ A,
                                               const ushort* __restrict__ B,
                                               const float* __restrict__ bias0,
                                               const float* __restrict__ bias1,
                                               const float* __restrict__ bias2,
                                               void* __restrict__ Cout) {
  const int K = DIM;
  const int MT = LSEQ / 128;            // 28
  const int ntiles = MT * (SEGS * DIM / 128);
  __shared__ __attribute__((aligned(16))) ushort As[128 * 64];
  __shared__ __attribute__((aligned(16))) ushort Bs[128 * 64];
  const int tid  = threadIdx.x;
  const int lane = tid & 63;
  const int wid  = tid >> 6;
  const int wm = (wid >> 1) * 64;
  const int wn = (wid & 1) * 64;
  const int lr = lane & 15;
  const int lg = lane >> 4;
  // staging geometry: chunk = 8 rows x 64 cols (1 KB); lane covers 16 B
  const int srow = lane >> 3;           // row within chunk (0..7)
  const int sbyte = (lane & 7) * 16;    // byte col within row
  const int ssrc = (sbyte ^ (srow << 4)) >> 1;  // pre-swizzled ushort col

  for (int tile = blockIdx.x; tile < ntiles; tile += gridDim.x) {
    const int m0 = (tile % MT) * 128;
    const int n0 = (tile / MT) * 128;   // consecutive blocks share B panel

    f32x4 acc[4][4] = {};

    for (int kt = 0; kt < K; kt += 64) {
      __syncthreads();
#pragma unroll
      for (int i = 0; i < 4; ++i) {
        int chunk = wid * 4 + i;               // 0..15 -> rows [chunk*8, +8)
        int row = chunk * 8 + srow;
        const ushort* ga = A + (size_t)(m0 + row) * K + kt + ssrc;
        const ushort* gb = B + (size_t)(n0 + row) * K + kt + ssrc;
        __builtin_amdgcn_global_load_lds(
            (__attribute__((address_space(1))) void*)(void*)ga,
            (__attribute__((address_space(3))) void*)(&As[chunk * 512]), 16, 0, 0);
        __builtin_amdgcn_global_load_lds(
            (__attribute__((address_space(1))) void*)(void*)gb,
            (__attribute__((address_space(3))) void*)(&Bs[chunk * 512]), 16, 0, 0);
      }
      __syncthreads();

#pragma unroll
      for (int kk = 0; kk < 2; ++kk) {
        bf16x8 af[4], bfr[4];
        const int cb = lg * 16 + kk * 64;      // byte col of this lane's frag
#pragma unroll
        for (int m = 0; m < 4; ++m) {
          int row = wm + m * 16 + lr;
          af[m] = *reinterpret_cast<const bf16x8*>(
              (const char*)As + row * 128 + (cb ^ ((row & 7) << 4)));
        }
#pragma unroll
        for (int n = 0; n < 4; ++n) {
          int row = wn + n * 16 + lr;
          bfr[n] = *reinterpret_cast<const bf16x8*>(
              (const char*)Bs + row * 128 + (cb ^ ((row & 7) << 4)));
        }
#pragma unroll
        for (int m = 0; m < 4; ++m)
#pragma unroll
          for (int n = 0; n < 4; ++n)
            acc[m][n] = __builtin_amdgcn_mfma_f32_16x16x32_bf16(af[m], bfr[n], acc[m][n], 0, 0, 0);
      }
    }

    int seg = 0;
    const float* bp = bias0;
    if (SEGS == 3) {
      seg = n0 >= 2 * DIM ? 2 : (n0 >= DIM ? 1 : 0);
      bp = seg == 0 ? bias0 : (seg == 1 ? bias1 : bias2);
    }
    const int nbase = n0 - seg * DIM;

#pragma unroll
    for (int m = 0; m < 4; ++m) {
#pragma unroll
      for (int n = 0; n < 4; ++n) {
        int col = nbase + wn + n * 16 + lr;
        float bvv = bp[col];
#pragma unroll
        for (int r = 0; r < 4; ++r) {
          int row = m0 + wm + m * 16 + lg * 4 + r;
          float v = acc[m][n][r] + bvv;
          if (OUT_F32)
            ((float*)Cout)[(size_t)row * DIM + col] = v;
          else
            ((ushort*)Cout)[(size_t)seg * ((size_t)LSEQ * DIM) + (size_t)row * DIM + col] = f2bf(v);
        }
      }
    }
    __syncthreads();  // all reads of As/Bs done before next tile stages
  }
}

// ---------------- RMSNorm(full 1536) + 3D RoPE, in place on bf16 ----------------
__global__ __launch_bounds__(256) void normrope(ushort* __restrict__ Qb,
                                                ushort* __restrict__ Kb,
                                                const float* __restrict__ gq,
                                                const float* __restrict__ gk,
                                                const float* __restrict__ cosT,
                                                const float* __restrict__ sinT) {
  __shared__ float red[4];
  const int l = blockIdx.x;
  const int tid = threadIdx.x;
  ushort* row = (blockIdx.y == 0 ? Qb : Kb) + (size_t)l * DIM;
  const float* g = blockIdx.y == 0 ? gq : gk;

  const u32* rp = reinterpret_cast<const u32*>(row);
  u32 pk[3];
  float v[6];
#pragma unroll
  for (int i = 0; i < 3; ++i) {
    pk[i] = rp[tid * 3 + i];
    v[2 * i]     = bf2f((ushort)(pk[i] & 0xffff));
    v[2 * i + 1] = bf2f((ushort)(pk[i] >> 16));
  }
  float ss = 0.f;
#pragma unroll
  for (int i = 0; i < 6; ++i) ss += v[i] * v[i];
#pragma unroll
  for (int off = 1; off < 64; off <<= 1) ss += __shfl_xor(ss, off, 64);
  if ((tid & 63) == 0) red[tid >> 6] = ss;
  __syncthreads();
  float tot = red[0] + red[1] + red[2] + red[3];
  float rms = rsqrtf(tot * (1.0f / DIM) + 1e-6f);

  const int fi = l / 448;
  const int rem = l % 448;
  const int hi = rem / 28;
  const int wi = rem % 28;

  u32* wp = reinterpret_cast<u32*>(row);
#pragma unroll
  for (int i = 0; i < 3; ++i) {
    int p = tid * 3 + i;
    int head = p >> 6;
    int j = p & 63;
    int trow = (j < 22) ? fi : ((j < 43) ? hi : wi);
    float cv = cosT[trow * 64 + j];
    float sv = sinT[trow * 64 + j];
    int idx = head * 128 + 2 * j;
    float xr = v[2 * i] * rms * g[idx];
    float xi = v[2 * i + 1] * rms * g[idx + 1];
    float orr = xr * cv - xi * sv;
    float oii = xr * sv + xi * cv;
    wp[p] = (u32)f2bf(orr) | ((u32)f2bf(oii) << 16);
  }
}

// ---------------- flash attention: 4 waves x 32 q-rows, KVB=64, 32x32 MFMA.
// Ks AND Vt double-buffered -> ONE barrier per K-tile (race audit: writeV(buf)
// targets the Vt buffer last read two iterations ago, >=1 barrier in between;
// issueK after the barrier every wave reaches only after its reads of that
// Ks buffer; the barrier's vmcnt(0) drain covers DMA visibility).
// P in-register via permlane (T12). XCD-aware tile remap (T1).
#define QBLK 128
#define KVB  64

__global__ __launch_bounds__(256, 2) void attn(const ushort* __restrict__ Q,
                                               const ushort* __restrict__ Kp,
                                               const ushort* __restrict__ Vp,
                                               ushort* __restrict__ O,
                                               float* __restrict__ Opart,
                                               float* __restrict__ mlbuf,
                                               int nsplit) {
  __shared__ __attribute__((aligned(16))) ushort Ks[2][KVB * 128];  // 2x16KB
  __shared__ __attribute__((aligned(16))) ushort Vt[2][128][72];    // 2x18KB
  const int tid  = threadIdx.x;
  const int lane = tid & 63;
  const int wv   = tid >> 6;
  const int lq   = lane & 31;
  const int hi   = lane >> 5;
  const float scale = 0.08838834764831845f; // 1/sqrt(128)

  // T1: remap so each XCD gets a contiguous tile range (KV slice L2 reuse).
  const int per_xcd = gridDim.x >> 3;
  const int tile = (blockIdx.x & 7) * per_xcd + (blockIdx.x >> 3);
  const int qb    = tile % (LSEQ / QBLK);          // q-block fastest
  const int rest  = tile / (LSEQ / QBLK);
  const int h     = rest % HEADS;
  const int split = rest / HEADS;
  const int q0    = qb * QBLK;

  const int NT   = LSEQ / KVB;                 // 56 tiles
  const int t_lo = split * NT / nsplit;
  const int t_hi = (split + 1) * NT / nsplit;

  // Q fragments (B-operand): lane holds Q[q=lq][d = dstep*16 + hi*8 + j]
  bf16x8 qf[8];
  {
    const ushort* qbase = Q + (size_t)(q0 + wv * 32 + lq) * DIM + h * HD;
#pragma unroll
    for (int d = 0; d < 8; ++d)
      qf[d] = *reinterpret_cast<const bf16x8*>(qbase + d * 16 + hi * 8);
  }

  f32x16 accO[4] = {}; // [nd]: col d = nd*32+lq, row q = crow(r,hi)
  float m = -1e30f, lsum = 0.f;

  const int mbk = tid >> 4;  // 0..15 -> kv rows [4*mbk, +4)
  const int mbd = tid & 15;  // 0..15 -> d cols  [8*mbd, +8)

  uint4 vr0, vr1, vr2, vr3;  // next tile's V rows (4x8 micro-block)
  auto issueK = [&](int t, int nb) {
    const int kv0 = t * KVB;
#pragma unroll
    for (int i = 0; i < 4; ++i) {
      int o16 = (wv * 4 + i) * 64 + lane;        // 16B-unit index in tile
      int r = o16 >> 4;
      int b = (o16 & 15) * 16;                   // byte col within row
      int srcu = (b ^ ((r & 7) << 4)) >> 1;      // pre-swizzled ushort col
      const ushort* gp = Kp + (size_t)(kv0 + r) * DIM + h * HD + srcu;
      __builtin_amdgcn_global_load_lds(
          (__attribute__((address_space(1))) void*)(void*)gp,
          (__attribute__((address_space(3))) void*)(&Ks[nb][(wv * 4 + i) * 512]), 16, 0, 0);
    }
  };
  auto loadV = [&](int t) {
    const ushort* vbase = Vp + (size_t)(t * KVB + mbk * 4) * DIM + h * HD + mbd * 8;
    vr0 = *reinterpret_cast<const uint4*>(vbase);
    vr1 = *reinterpret_cast<const uint4*>(vbase + DIM);
    vr2 = *reinterpret_cast<const uint4*>(vbase + 2 * DIM);
    vr3 = *reinterpret_cast<const uint4*>(vbase + 3 * DIM);
  };
  auto writeV = [&](int nb) {
    const ushort* s0 = reinterpret_cast<const ushort*>(&vr0);
    const ushort* s1 = reinterpret_cast<const ushort*>(&vr1);
    const ushort* s2 = reinterpret_cast<const ushort*>(&vr2);
    const ushort* s3 = reinterpret_cast<const ushort*>(&vr3);
#pragma unroll
    for (int jj = 0; jj < 8; ++jj) {
      int j = (jj + mbd) & 7;  // rotate write order to spread banks
      uint2 w;
      w.x = (u32)s0[j] | ((u32)s1[j] << 16);
      w.y = (u32)s2[j] | ((u32)s3[j] << 16);
      *reinterpret_cast<uint2*>(&Vt[nb][mbd * 8 + j][mbk * 4]) = w;
    }
  };

  issueK(t_lo, 0);
  loadV(t_lo);

  int buf = 0;
  for (int t = t_lo; t < t_hi; ++t) {
    writeV(buf);       // waits vr* (vmcnt); Vt[buf] last READ at iter t-2
    __syncthreads();   // single barrier: drains K DMA(t) + makes Vt[buf] visible

    if (t + 1 < t_hi) {      // prefetch next tile; lands during compute
      issueK(t + 1, buf ^ 1);
      loadV(t + 1);
    }

    // ---- two sequential 32-k subtiles (one sv live) ----
#pragma unroll
    for (int hf = 0; hf < 2; ++hf) {
      f32x16 sv = {};
      __builtin_amdgcn_s_setprio(1);
#pragma unroll
      for (int d = 0; d < 8; ++d) {
        int db = d * 32 + hi * 16;   // byte col of this lane's 16B A-chunk
        const bf16x8 a = *reinterpret_cast<const bf16x8*>(
            (const char*)&Ks[buf][0] + (hf * 32 + lq) * 256 + (db ^ ((lq & 7) << 4)));
        sv = __builtin_amdgcn_mfma_f32_32x32x16_bf16(a, qf[d], sv, 0, 0, 0);
      }
      __builtin_amdgcn_s_setprio(0);

      // softmax over this 32-k subtile (lane owns q-row; partner has other 16 k)
      float pmax = sv[0];
#pragma unroll
      for (int r = 1; r < 16; ++r) pmax = fmaxf(pmax, sv[r]);
      pmax = fmaxf(pmax, __shfl_xor(pmax, 32, 64));
      pmax *= scale;

      if (__any(pmax > m + 8.f)) {   // defer-max (T13)
        float mn = fmaxf(m, pmax);
        float al = __expf(m - mn);
        m = mn;
        lsum *= al;
#pragma unroll
        for (int r = 0; r < 16; ++r) {
          int qr = (r & 3) + 8 * (r >> 2) + 4 * hi;
          float alr = __shfl(al, qr, 64);
          accO[0][r] *= alr; accO[1][r] *= alr;
          accO[2][r] *= alr; accO[3][r] *= alr;
        }
      }

      float p[16];
      float psum = 0.f;
#pragma unroll
      for (int r = 0; r < 16; ++r) {
        p[r] = __expf(fmaf(sv[r], scale, -m));
        psum += p[r];
      }
      psum += __shfl_xor(psum, 32, 64);
      lsum += psum;

      // ---- in-register P -> A-fragment redistribution (T12) ----
      u32 a0 = pkbf(p[0], p[1]),   a1 = pkbf(p[2], p[3]);
      u32 a4 = pkbf(p[4], p[5]),   a5 = pkbf(p[6], p[7]);
      u32 c0 = pkbf(p[8], p[9]),   c1 = pkbf(p[10], p[11]);
      u32 c4 = pkbf(p[12], p[13]), c5 = pkbf(p[14], p[15]);
      plswap(a0, a4, hi);
      plswap(a1, a5, hi);
      plswap(c0, c4, hi);
      plswap(c1, c5, hi);
      u32x4 w0 = {a0, a1, a4, a5};
      u32x4 w1 = {c0, c1, c4, c5};
      bf16x8 pa0 = __builtin_bit_cast(bf16x8, w0);  // k [hf*32, +16)
      bf16x8 pa1 = __builtin_bit_cast(bf16x8, w1);  // k [hf*32+16, +16)

      // ---- PV over this 32-k subtile ----
      __builtin_amdgcn_s_setprio(1);
#pragma unroll
      for (int nd = 0; nd < 4; ++nd) {
        bf16x8 vb0 = *reinterpret_cast<const bf16x8*>(
            &Vt[buf][nd * 32 + lq][hf * 32 + hi * 8]);
        accO[nd] = __builtin_amdgcn_mfma_f32_32x32x16_bf16(pa0, vb0, accO[nd], 0, 0, 0);
      }
#pragma unroll
      for (int nd = 0; nd < 4; ++nd) {
        bf16x8 vb1 = *reinterpret_cast<const bf16x8*>(
            &Vt[buf][nd * 32 + lq][hf * 32 + 16 + hi * 8]);
        accO[nd] = __builtin_amdgcn_mfma_f32_32x32x16_bf16(pa1, vb1, accO[nd], 0, 0, 0);
      }
      __builtin_amdgcn_s_setprio(0);
    }

    buf ^= 1;   // no end barrier: dbuf on BOTH Ks and Vt makes it redundant
  }

  // ---- epilogue ----
  if (nsplit == 1) {
    float inv_own = 1.0f / lsum;
#pragma unroll
    for (int r = 0; r < 16; ++r) {
      int qr = (r & 3) + 8 * (r >> 2) + 4 * hi;
      float inv = __shfl(inv_own, qr, 64);
      ushort* orow = O + (size_t)(q0 + wv * 32 + qr) * DIM + h * HD;
#pragma unroll
      for (int nd = 0; nd < 4; ++nd)
        orow[nd * 32 + lq] = f2bf(accO[nd][r] * inv);
    }
  } else {
    float* Op = Opart + ((size_t)split * HEADS + h) * ((size_t)LSEQ * HD);
#pragma unroll
    for (int r = 0; r < 16; ++r) {
      int qr = (r & 3) + 8 * (r >> 2) + 4 * hi;
      float* orow = Op + (size_t)(q0 + wv * 32 + qr) * HD;
#pragma unroll
      for (int nd = 0; nd < 4; ++nd)
        orow[nd * 32 + lq] = accO[nd][r];
    }
    if (hi == 0) {
      size_t row = (size_t)split * (HEADS * LSEQ) + (size_t)h * LSEQ + (q0 + wv * 32 + lq);
      mlbuf[2 * row]     = m;
      mlbuf[2 * row + 1] = lsum;
    }
  }
}

// ---------------- merge of KV-split partials ----------------
__global__ __launch_bounds__(256) void attn_merge(const float* __restrict__ Opart,
                                                  const float* __restrict__ mlbuf,
                                                  ushort* __restrict__ Ob, int nsplit) {
  const int RN = HEADS * LSEQ;          // rows per split
  int gi = blockIdx.x * 256 + threadIdx.x;   // one float4 of one (h,q) row
  int row = gi >> 5;                    // h*LSEQ + q
  int d4 = (gi & 31) * 4;
  if (row >= RN) return;
  int h = row / LSEQ, q = row % LSEQ;

  float M = -1e30f;
  for (int s = 0; s < nsplit; ++s) M = fmaxf(M, mlbuf[2 * ((size_t)s * RN + row)]);
  float den = 0.f;
  float4 acc = {0.f, 0.f, 0.f, 0.f};
  for (int s = 0; s < nsplit; ++s) {
    float ms = mlbuf[2 * ((size_t)s * RN + row)];
    float ls = mlbuf[2 * ((size_t)s * RN + row) + 1];
    float w = __expf(ms - M);
    den += ls * w;
    const float4 o = *reinterpret_cast<const float4*>(
        &Opart[((size_t)s * RN + row) * HD + d4]);
    acc.x += w * o.x; acc.y += w * o.y; acc.z += w * o.z; acc.w += w * o.w;
  }
  float inv = 1.0f / den;
  ushort4 r;
  r.x = f2bf(acc.x * inv); r.y = f2bf(acc.y * inv);
  r.z = f2bf(acc.z * inv); r.w = f2bf(acc.w * inv);
  *reinterpret_cast<ushort4*>(&Ob[(size_t)q * DIM + h * HD + d4]) = r;
}

// ---------------- launch ----------------
extern "C" void kernel_launch(void* const* d_in, const int* in_sizes, int n_in,
                              void* d_out, int out_size, void* d_ws, size_t ws_size,
                              hipStream_t stream) {
  (void)in_sizes; (void)n_in; (void)out_size;
  const float* x    = (const float*)d_in[0];
  const float* cosT = (const float*)d_in[1];
  const float* sinT = (const float*)d_in[2];
  const float* Wq   = (const float*)d_in[3];
  const float* bq   = (const float*)d_in[4];
  const float* Wk   = (const float*)d_in[5];
  const float* bk   = (const float*)d_in[6];
  const float* Wv   = (const float*)d_in[7];
  const float* bv_in = (const float*)d_in[8];
  const float* Wo   = (const float*)d_in[9];
  const float* bo   = (const float*)d_in[10];
  const float* gq   = (const float*)d_in[11];
  const float* gk   = (const float*)d_in[12];

  const size_t LD = (size_t)LSEQ * DIM;
  const size_t WD = (size_t)DIM * DIM;
  const size_t base_bytes = (5 * LD + 4 * WD) * sizeof(ushort);
  if (ws_size < base_bytes) return;

  ushort* xb  = (ushort*)d_ws;
  ushort* Wqb = xb + LD;        // Wqb, Wkb, Wvb, Wob contiguous
  ushort* Wob = Wqb + 3 * WD;
  ushort* Qb  = Wob + WD;       // Qb, Kb, Vb contiguous (fused C)
  ushort* Kb  = Qb + LD;
  ushort* Vb  = Kb + LD;
  ushort* Ob  = Vb + LD;

  // KV-split sizing from available workspace (deterministic in ws_size)
  const size_t RN = (size_t)HEADS * LSEQ;              // 43008 rows
  const size_t split_bytes = RN * HD * 4 + RN * 8;     // O partial + (m,l)
  int nsplit = 1;
  if (ws_size >= base_bytes + 3 * split_bytes) nsplit = 3;
  else if (ws_size >= base_bytes + 2 * split_bytes) nsplit = 2;
  float* Opart = (float*)((char*)d_ws + base_bytes);
  float* mlbuf = Opart + (size_t)nsplit * RN * HD;

  cvt_f32_bf16<<<(int)(LD / 4 / 256), 256, 0, stream>>>(x, xb, (int)LD);
  cvt_w4<<<(int)(4 * WD / 4 / 256), 256, 0, stream>>>(Wq, Wk, Wv, Wo, Wqb);

  // fused QKV projection: 1008 tiles on a 768-block persistent grid
  {
    int nt = (LSEQ / 128) * (3 * DIM / 128);
    gemm_bt<3, false><<<nt < 768 ? nt : 768, 256, 0, stream>>>(
        xb, Wqb, bq, bk, bv_in, Qb);
  }

  normrope<<<dim3(LSEQ, 2), 256, 0, stream>>>(Qb, Kb, gq, gk, cosT, sinT);

  // 1D grid, XCD-remapped inside the kernel (336*nsplit divisible by 8)
  attn<<<(LSEQ / QBLK) * HEADS * nsplit, 256, 0, stream>>>(
      Qb, Kb, Vb, Ob, Opart, mlbuf, nsplit);
  if (nsplit > 1)
    attn_merge<<<(int)(RN * 32 / 256), 256, 0, stream>>>(Opart, mlbuf, Ob, nsplit);

  {
    int nt = (LSEQ / 128) * (DIM / 128);   // 336 tiles
    gemm_bt<1, true><<<nt < 768 ? nt : 768, 256, 0, stream>>>(
        Ob, Wob, bo, bo, bo, d_out);
  }
}